// Round 11
// baseline (7925.219 us; speedup 1.0000x reference)
//
#include <hip/hip_runtime.h>
#include <hip/hip_bf16.h>

typedef unsigned short u16;
typedef unsigned int   u32;
typedef unsigned long long u64;
typedef __attribute__((ext_vector_type(8))) __bf16 bf16x8;
typedef __attribute__((ext_vector_type(4))) float   f32x4;

// async global->LDS, 16B per lane; LDS dest = wave-uniform base + lane*16
#define GLOAD16(gp, lp) __builtin_amdgcn_global_load_lds( \
    (__attribute__((address_space(1))) void*)(gp),        \
    (__attribute__((address_space(3))) void*)(lp), 16, 0, 0)

static __device__ __forceinline__ u16 f2bf(float f) {
  __bf16 b = (__bf16)f;                 // RNE convert
  return __builtin_bit_cast(u16, b);
}
static __device__ __forceinline__ f32x4 mfma16(bf16x8 a, bf16x8 b, f32x4 c) {
  return __builtin_amdgcn_mfma_f32_16x16x32_bf16(a, b, c, 0, 0, 0);
}

// ---------------- prep kernels ----------------

__global__ __launch_bounds__(256) void k_cvt_emb(const float* __restrict__ s,
                                                 u16* __restrict__ d) {
  int i = (blockIdx.x * 256 + threadIdx.x) * 4;
  float4 v = *(const float4*)(s + i);
  d[i] = f2bf(v.x); d[i+1] = f2bf(v.y); d[i+2] = f2bf(v.z); d[i+3] = f2bf(v.w);
}

__global__ __launch_bounds__(256) void k_tr_wh(const float* __restrict__ Wh,
                                               u16* __restrict__ WhxT,
                                               u16* __restrict__ WhhT) {
  __shared__ float tile[32][33];
  int bx = blockIdx.x & 31;
  int be = blockIdx.x >> 5;
  int tx = threadIdx.x & 31, ty = threadIdx.x >> 5;
  #pragma unroll
  for (int s = 0; s < 32; s += 8)
    tile[ty + s][tx] = Wh[(size_t)(be*32 + ty + s) * 1024 + bx*32 + tx];
  __syncthreads();
  #pragma unroll
  for (int s = 0; s < 32; s += 8) {
    int e = be*32 + tx;
    int j = bx*32 + ty + s;
    u16 v = f2bf(tile[tx][ty + s]);
    if (e < 512) WhxT[(size_t)j * 512 + e] = v;
    else         WhhT[(size_t)j * 1024 + (e - 512)] = v;
  }
}

__global__ __launch_bounds__(256) void k_tr_wo(const float* __restrict__ Wo,
                                               u16* __restrict__ WoT) {
  __shared__ float tile[32][33];
  int bx = blockIdx.x & 255;
  int by = blockIdx.x >> 8;
  int tx = threadIdx.x & 31, ty = threadIdx.x >> 5;
  #pragma unroll
  for (int s = 0; s < 32; s += 8)
    tile[ty + s][tx] = Wo[(size_t)(by*32 + ty + s) * 8192 + bx*32 + tx];
  __syncthreads();
  #pragma unroll
  for (int s = 0; s < 32; s += 8)
    WoT[(size_t)(bx*32 + ty + s) * 1024 + by*32 + tx] = f2bf(tile[tx][ty + s]);
}

// h0 -> ring slot 0; zero flags region (incl. worker queue counter at [2047])
__global__ __launch_bounds__(256) void k_init(const float* __restrict__ hid,
                                              u16* __restrict__ ring,
                                              unsigned* __restrict__ flags) {
  int i = blockIdx.x * 256 + threadIdx.x;
  ring[i] = f2bf(hid[i]);
  if (blockIdx.x < 8) flags[i] = 0;
}

// ---------------- phase 1: xpart = gather(emb) @ WhxT^T + b_h ----------------
__global__ __launch_bounds__(256) void k_xpart(const int* __restrict__ xq,
                                               const u16* __restrict__ embB,
                                               const u16* __restrict__ WhxT,
                                               const float* __restrict__ bh,
                                               float* __restrict__ xpart) {
  __shared__ __align__(16) u16 As[128 * 32];
  __shared__ __align__(16) u16 Bs[128 * 32];
  __shared__ int sx[128];
  int bid = blockIdx.x;
  int cpx = gridDim.x >> 3;
  int swz = (bid & 7) * cpx + (bid >> 3);
  int tm = (swz >> 3) * 128, tn = (swz & 7) * 128;
  int tid = threadIdx.x, lane = tid & 63, w = tid >> 6;
  int wm = (w >> 1) * 64, wn = (w & 1) * 64;
  if (tid < 128) sx[tid] = xq[tm + tid];
  __syncthreads();
  int r0 = tid >> 2, sub = tid & 3;
  const u16* ga0 = embB + (size_t)sx[r0] * 512 + sub * 8;
  const u16* ga1 = embB + (size_t)sx[64 + r0] * 512 + sub * 8;
  const u16* gb0 = WhxT + (size_t)(tn + r0) * 512 + sub * 8;
  const u16* gb1 = WhxT + (size_t)(tn + 64 + r0) * 512 + sub * 8;
  f32x4 acc[4][4] = {};
  int rl = lane & 15, kb = (lane >> 4) * 8;
  for (int kt = 0; kt < 16; ++kt) {
    int k0 = kt * 32;
    __syncthreads();
    GLOAD16(ga0 + k0, As + w * 512);
    GLOAD16(ga1 + k0, As + 2048 + w * 512);
    GLOAD16(gb0 + k0, Bs + w * 512);
    GLOAD16(gb1 + k0, Bs + 2048 + w * 512);
    __syncthreads();
    bf16x8 af[4], bf[4];
    #pragma unroll
    for (int mi = 0; mi < 4; mi++) af[mi] = *(const bf16x8*)&As[(wm + mi*16 + rl) * 32 + kb];
    #pragma unroll
    for (int ni = 0; ni < 4; ni++) bf[ni] = *(const bf16x8*)&Bs[(wn + ni*16 + rl) * 32 + kb];
    #pragma unroll
    for (int mi = 0; mi < 4; mi++)
      #pragma unroll
      for (int ni = 0; ni < 4; ni++)
        acc[mi][ni] = mfma16(af[mi], bf[ni], acc[mi][ni]);
  }
  int rq = (lane >> 4) << 2;
  #pragma unroll
  for (int ni = 0; ni < 4; ni++) {
    int col = tn + wn + ni*16 + rl;
    float bias = bh[col];
    #pragma unroll
    for (int mi = 0; mi < 4; mi++) {
      int row = tm + wm + mi*16 + rq;
      #pragma unroll
      for (int r = 0; r < 4; r++)
        xpart[(size_t)(row + r) * 1024 + col] = acc[mi][ni][r] + bias;
    }
  }
}

// ---------------- phase 2+3 fused persistent kernel ----------------
// Grid 1024 x 256thr, __launch_bounds__(256,4): VGPR capped at 128 => 4
// blocks/CU => all 1024 blocks co-resident BY CONSTRUCTION (no dispatch-order
// assumption). Blocks 0..63: the r5-proven rnn role (unchanged). Blocks
// 64..1023: persistent logits workers — claim 128x64 output tiles from a
// global queue (t ascending), gate on the rnn flags (tile tIdx needs ring
// slots <= 4*tIdx+4), compute, repeat. Workers never block the rnn; same-
// stream concurrency achieved inside one kernel (r10 lesson: separate
// kernels on one stream serialize).
__global__ __launch_bounds__(256, 4) void k_fused(const u16* __restrict__ WhhT,
                                                  const float* __restrict__ xpart,
                                                  u16* __restrict__ ring,
                                                  float* __restrict__ hfinal,
                                                  unsigned* flags,
                                                  const u16* __restrict__ WoT,
                                                  const float* __restrict__ bo,
                                                  float* __restrict__ C) {
  __shared__ __align__(16) u16 smem[6144];        // union: rnn psh 8KB | As 8KB + Bs 4KB
  __shared__ int sq;
  const int tid = threadIdx.x, lane = tid & 63, w = tid >> 6;

  if (blockIdx.x < 64) {
    // ================= rnn role (r5 structure, verbatim) =================
    float* psh = (float*)smem;
    int bid = blockIdx.x;
    int jbase = bid * 16;
    const int rl = lane & 15;
    const int kbase = w * 256 + ((lane >> 4) << 3);
    bf16x8 Wreg[8];
    #pragma unroll
    for (int ki = 0; ki < 8; ++ki)
      Wreg[ki] = *(const bf16x8*)&WhhT[(size_t)(jbase + rl) * 1024 + kbase + ki * 32];
    const bool red = (tid < 128);
    int b = 0, jq = 0, mi = 0, lsrc = 0, rg = 0;
    float4 xpre = make_float4(0.f, 0.f, 0.f, 0.f);
    if (red) {
      b = tid >> 2; jq = (tid & 3) << 2;
      mi = b >> 4;
      int bb = b & 15;
      lsrc = (bb >> 2) << 4;
      rg = bb & 3;
      xpre = *(const float4*)&xpart[(size_t)(b * 1024 + 0) * 1024 + jbase + jq];
    }
    for (int t = 0; t < 1024; ++t) {
      const u16* hprev = ring + (size_t)t * 32768;
      bf16x8 ha[16];
      #pragma unroll
      for (int ki = 0; ki < 8; ++ki) {
        int k = kbase + ki * 32;
        ha[ki*2 + 0] = *(const bf16x8*)&hprev[(size_t)rl * 1024 + k];
        ha[ki*2 + 1] = *(const bf16x8*)&hprev[(size_t)(16 + rl) * 1024 + k];
      }
      f32x4 acc0 = {0.f, 0.f, 0.f, 0.f}, acc1 = {0.f, 0.f, 0.f, 0.f};
      #pragma unroll
      for (int ki = 0; ki < 8; ++ki) {
        acc0 = mfma16(ha[ki*2 + 0], Wreg[ki], acc0);
        acc1 = mfma16(ha[ki*2 + 1], Wreg[ki], acc1);
      }
      *(f32x4*)&psh[((w * 2 + 0) * 64 + lane) * 4] = acc0;
      *(f32x4*)&psh[((w * 2 + 1) * 64 + lane) * 4] = acc1;
      __syncthreads();
      if (red) {
        float s0 = 0.f, s1 = 0.f, s2 = 0.f, s3 = 0.f;
        #pragma unroll
        for (int ww = 0; ww < 4; ++ww) {
          const float* pp = &psh[((ww * 2 + mi) * 64) * 4];
          s0 += pp[(lsrc + jq + 0) * 4 + rg];
          s1 += pp[(lsrc + jq + 1) * 4 + rg];
          s2 += pp[(lsrc + jq + 2) * 4 + rg];
          s3 += pp[(lsrc + jq + 3) * 4 + rg];
        }
        float v0 = tanhf(s0 + xpre.x);
        float v1 = tanhf(s1 + xpre.y);
        float v2 = tanhf(s2 + xpre.z);
        float v3 = tanhf(s3 + xpre.w);
        u32 lo = (u32)f2bf(v0) | ((u32)f2bf(v1) << 16);
        u32 hi = (u32)f2bf(v2) | ((u32)f2bf(v3) << 16);
        u64 hv = (u64)lo | ((u64)hi << 32);
        __hip_atomic_store((u64*)(ring + (size_t)(t + 1) * 32768 + b * 1024 + jbase + jq),
                           hv, __ATOMIC_RELAXED, __HIP_MEMORY_SCOPE_AGENT);
        if (t == 1023)
          *(float4*)&hfinal[b * 1024 + jbase + jq] = make_float4(v0, v1, v2, v3);
      }
      if (t < 1023) {
        asm volatile("s_waitcnt vmcnt(0)" ::: "memory");
        __syncthreads();
        if (tid == 0)
          __hip_atomic_store(&flags[bid * 32], (unsigned)(t + 1),
                             __ATOMIC_RELAXED, __HIP_MEMORY_SCOPE_AGENT);
        if (red)
          xpre = *(const float4*)&xpart[((size_t)(b * 1024 + (t + 1))) * 1024 + jbase + jq];
        if (w == 0) {
          while (__hip_atomic_load(&flags[lane * 32], __ATOMIC_RELAXED,
                                   __HIP_MEMORY_SCOPE_AGENT) < (unsigned)(t + 1)) { }
        }
        __syncthreads();
      } else {
        // final publish: slot 1024 drained -> flag 1024 (workers' last gate)
        asm volatile("s_waitcnt vmcnt(0)" ::: "memory");
        __syncthreads();
        if (tid == 0)
          __hip_atomic_store(&flags[bid * 32], 1024u,
                             __ATOMIC_RELAXED, __HIP_MEMORY_SCOPE_AGENT);
      }
    }
    return;
  }

  // ================= logits worker role =================
  // Tile q: tIdx = q>>7 (128 A-rows = ring slots 4t+1..4t+4), vIdx = q&127
  // (64 Wo cols). Gate: all 64 flags >= 4*tIdx+4 (sleep-poll, low pressure).
  u16* As = smem;                 // 128x32
  u16* Bs = smem + 4096;          // 64x32
  unsigned* qctr = flags + 2047;
  const u16* A = ring + 32768;    // A row m -> (t=m>>5, b=m&31)
  const int wm = (w >> 1) * 64, wn = (w & 1) * 32;
  const int r0 = tid >> 2, sub = tid & 3;
  const int rl = lane & 15, kb = (lane >> 4) * 8;
  const int rq = (lane >> 4) << 2;
  for (;;) {
    if (tid == 0)
      sq = (int)__hip_atomic_fetch_add(qctr, 1u, __ATOMIC_RELAXED,
                                       __HIP_MEMORY_SCOPE_AGENT);
    __syncthreads();
    const int q = sq;
    if (q >= 32768) return;
    const int tIdx = q >> 7, vIdx = q & 127;
    const int tm = tIdx * 128, tn = vIdx * 64;
    // ---- gate ----
    if (tid < 64) {
      unsigned tgt = (unsigned)(tIdx * 4 + 4);    // 1024 for tIdx=255
      const unsigned* fp = flags + tid * 32;
      for (;;) {
        unsigned v = __hip_atomic_load(fp, __ATOMIC_RELAXED, __HIP_MEMORY_SCOPE_AGENT);
        if (!__any((int)(v < tgt))) break;
        __builtin_amdgcn_s_sleep(127);
      }
    }
    __syncthreads();
    // ---- compute 128x64 tile ----
    const u16* ga0 = A + (size_t)(tm + r0) * 1024 + sub * 8;
    const u16* ga1 = A + (size_t)(tm + 64 + r0) * 1024 + sub * 8;
    const u16* gb0 = WoT + (size_t)(tn + r0) * 1024 + sub * 8;
    f32x4 acc[4][2] = {};
    for (int kt = 0; kt < 32; ++kt) {
      int k0 = kt * 32;
      __syncthreads();
      GLOAD16(ga0 + k0, As + w * 512);
      GLOAD16(ga1 + k0, As + 2048 + w * 512);
      GLOAD16(gb0 + k0, Bs + w * 512);
      __syncthreads();
      bf16x8 af[4], bf[2];
      #pragma unroll
      for (int mi = 0; mi < 4; mi++) af[mi] = *(const bf16x8*)&As[(wm + mi*16 + rl) * 32 + kb];
      #pragma unroll
      for (int ni = 0; ni < 2; ni++) bf[ni] = *(const bf16x8*)&Bs[(wn + ni*16 + rl) * 32 + kb];
      #pragma unroll
      for (int mi = 0; mi < 4; mi++)
        #pragma unroll
        for (int ni = 0; ni < 2; ni++)
          acc[mi][ni] = mfma16(af[mi], bf[ni], acc[mi][ni]);
    }
    #pragma unroll
    for (int ni = 0; ni < 2; ni++) {
      int col = tn + wn + ni*16 + rl;
      float bias = bo[col];
      #pragma unroll
      for (int mi = 0; mi < 4; mi++) {
        int row = tm + wm + mi*16 + rq;
        #pragma unroll
        for (int r = 0; r < 4; r++) {
          int m = row + r;
          size_t orow = (size_t)(((m & 31) << 10) | (m >> 5));
          C[orow * 8192 + col] = acc[mi][ni][r] + bias;
        }
      }
    }
  }
}

// ---------------- launch ----------------
extern "C" void kernel_launch(void* const* d_in, const int* in_sizes, int n_in,
                              void* d_out, int out_size, void* d_ws, size_t ws_size,
                              hipStream_t stream) {
  const int*   x   = (const int*)  d_in[0];
  const float* hid = (const float*)d_in[1];
  const float* emb = (const float*)d_in[2];
  const float* Wh  = (const float*)d_in[3];
  const float* bh  = (const float*)d_in[4];
  const float* Wo  = (const float*)d_in[5];
  const float* bo  = (const float*)d_in[6];
  float* logits = (float*)d_out;                       // [32768][8192]
  float* hfinal = logits + (size_t)32768 * 8192;       // [32][1024]

  char* ws = (char*)d_ws;
  size_t off = 0;
  auto alloc = [&](size_t bytes) {
    char* p = ws + off;
    off += (bytes + 255) & ~(size_t)255;
    return p;
  };
  u16*   embB  = (u16*)  alloc((size_t)8192 * 512 * 2);    //  8 MB
  u16*   WhxT  = (u16*)  alloc((size_t)1024 * 512 * 2);    //  1 MB
  u16*   WhhT  = (u16*)  alloc((size_t)1024 * 1024 * 2);   //  2 MB
  u16*   WoT   = (u16*)  alloc((size_t)8192 * 1024 * 2);   // 16 MB
  float* xpart = (float*)alloc((size_t)32768 * 1024 * 4);  // 128 MB, row=b*1024+t
  u16*   ring  = (u16*)  alloc((size_t)1025 * 32768 * 2);  // 67.1 MB (slot t = h_t)
  unsigned* flags = (unsigned*)alloc(8192);                // 64 flags + qctr
  (void)ws_size; (void)in_sizes; (void)n_in; (void)out_size;

  k_cvt_emb<<<4096, 256, 0, stream>>>(emb, embB);
  k_tr_wh  <<<1536, 256, 0, stream>>>(Wh, WhxT, WhhT);
  k_tr_wo  <<<8192, 256, 0, stream>>>(Wo, WoT);
  k_init   <<<128,  256, 0, stream>>>(hid, ring, flags);
  k_xpart  <<<2048, 256, 0, stream>>>(x, embB, WhxT, bh, xpart);
  k_fused  <<<1024, 256, 0, stream>>>(WhhT, xpart, ring, hfinal, flags,
                                      WoT, bo, logits);
}

// Round 12
// 4471.405 us; speedup vs baseline: 1.7724x; 1.7724x over previous
//
#include <hip/hip_runtime.h>
#include <hip/hip_bf16.h>

typedef unsigned short u16;
typedef unsigned int   u32;
typedef unsigned long long u64;
typedef __attribute__((ext_vector_type(8))) __bf16 bf16x8;
typedef __attribute__((ext_vector_type(4))) float   f32x4;

// async global->LDS, 16B per lane; LDS dest = wave-uniform base + lane*16
#define GLOAD16(gp, lp) __builtin_amdgcn_global_load_lds( \
    (__attribute__((address_space(1))) void*)(gp),        \
    (__attribute__((address_space(3))) void*)(lp), 16, 0, 0)

static __device__ __forceinline__ u16 f2bf(float f) {
  __bf16 b = (__bf16)f;                 // RNE convert
  return __builtin_bit_cast(u16, b);
}
static __device__ __forceinline__ f32x4 mfma16(bf16x8 a, bf16x8 b, f32x4 c) {
  return __builtin_amdgcn_mfma_f32_16x16x32_bf16(a, b, c, 0, 0, 0);
}

// ---------------- prep kernels ----------------

__global__ __launch_bounds__(256) void k_cvt_emb(const float* __restrict__ s,
                                                 u16* __restrict__ d) {
  int i = (blockIdx.x * 256 + threadIdx.x) * 4;
  float4 v = *(const float4*)(s + i);
  d[i] = f2bf(v.x); d[i+1] = f2bf(v.y); d[i+2] = f2bf(v.z); d[i+3] = f2bf(v.w);
}

__global__ __launch_bounds__(256) void k_tr_wh(const float* __restrict__ Wh,
                                               u16* __restrict__ WhxT,
                                               u16* __restrict__ WhhT) {
  __shared__ float tile[32][33];
  int bx = blockIdx.x & 31;
  int be = blockIdx.x >> 5;
  int tx = threadIdx.x & 31, ty = threadIdx.x >> 5;
  #pragma unroll
  for (int s = 0; s < 32; s += 8)
    tile[ty + s][tx] = Wh[(size_t)(be*32 + ty + s) * 1024 + bx*32 + tx];
  __syncthreads();
  #pragma unroll
  for (int s = 0; s < 32; s += 8) {
    int e = be*32 + tx;
    int j = bx*32 + ty + s;
    u16 v = f2bf(tile[tx][ty + s]);
    if (e < 512) WhxT[(size_t)j * 512 + e] = v;
    else         WhhT[(size_t)j * 1024 + (e - 512)] = v;
  }
}

__global__ __launch_bounds__(256) void k_tr_wo(const float* __restrict__ Wo,
                                               u16* __restrict__ WoT) {
  __shared__ float tile[32][33];
  int bx = blockIdx.x & 255;
  int by = blockIdx.x >> 8;
  int tx = threadIdx.x & 31, ty = threadIdx.x >> 5;
  #pragma unroll
  for (int s = 0; s < 32; s += 8)
    tile[ty + s][tx] = Wo[(size_t)(by*32 + ty + s) * 8192 + bx*32 + tx];
  __syncthreads();
  #pragma unroll
  for (int s = 0; s < 32; s += 8)
    WoT[(size_t)(bx*32 + ty + s) * 1024 + by*32 + tx] = f2bf(tile[tx][ty + s]);
}

// h0 -> ring slot 0; zero flags region (incl. worker queue counter at [2047])
__global__ __launch_bounds__(256) void k_init(const float* __restrict__ hid,
                                              u16* __restrict__ ring,
                                              unsigned* __restrict__ flags) {
  int i = blockIdx.x * 256 + threadIdx.x;
  ring[i] = f2bf(hid[i]);
  if (blockIdx.x < 8) flags[i] = 0;
}

// ---------------- phase 1: xpart = gather(emb) @ WhxT^T + b_h ----------------
__global__ __launch_bounds__(256) void k_xpart(const int* __restrict__ xq,
                                               const u16* __restrict__ embB,
                                               const u16* __restrict__ WhxT,
                                               const float* __restrict__ bh,
                                               float* __restrict__ xpart) {
  __shared__ __align__(16) u16 As[128 * 32];
  __shared__ __align__(16) u16 Bs[128 * 32];
  __shared__ int sx[128];
  int bid = blockIdx.x;
  int cpx = gridDim.x >> 3;
  int swz = (bid & 7) * cpx + (bid >> 3);
  int tm = (swz >> 3) * 128, tn = (swz & 7) * 128;
  int tid = threadIdx.x, lane = tid & 63, w = tid >> 6;
  int wm = (w >> 1) * 64, wn = (w & 1) * 64;
  if (tid < 128) sx[tid] = xq[tm + tid];
  __syncthreads();
  int r0 = tid >> 2, sub = tid & 3;
  const u16* ga0 = embB + (size_t)sx[r0] * 512 + sub * 8;
  const u16* ga1 = embB + (size_t)sx[64 + r0] * 512 + sub * 8;
  const u16* gb0 = WhxT + (size_t)(tn + r0) * 512 + sub * 8;
  const u16* gb1 = WhxT + (size_t)(tn + 64 + r0) * 512 + sub * 8;
  f32x4 acc[4][4] = {};
  int rl = lane & 15, kb = (lane >> 4) * 8;
  for (int kt = 0; kt < 16; ++kt) {
    int k0 = kt * 32;
    __syncthreads();
    GLOAD16(ga0 + k0, As + w * 512);
    GLOAD16(ga1 + k0, As + 2048 + w * 512);
    GLOAD16(gb0 + k0, Bs + w * 512);
    GLOAD16(gb1 + k0, Bs + 2048 + w * 512);
    __syncthreads();
    bf16x8 af[4], bf[4];
    #pragma unroll
    for (int mi = 0; mi < 4; mi++) af[mi] = *(const bf16x8*)&As[(wm + mi*16 + rl) * 32 + kb];
    #pragma unroll
    for (int ni = 0; ni < 4; ni++) bf[ni] = *(const bf16x8*)&Bs[(wn + ni*16 + rl) * 32 + kb];
    #pragma unroll
    for (int mi = 0; mi < 4; mi++)
      #pragma unroll
      for (int ni = 0; ni < 4; ni++)
        acc[mi][ni] = mfma16(af[mi], bf[ni], acc[mi][ni]);
  }
  int rq = (lane >> 4) << 2;
  #pragma unroll
  for (int ni = 0; ni < 4; ni++) {
    int col = tn + wn + ni*16 + rl;
    float bias = bh[col];
    #pragma unroll
    for (int mi = 0; mi < 4; mi++) {
      int row = tm + wm + mi*16 + rq;
      #pragma unroll
      for (int r = 0; r < 4; r++)
        xpart[(size_t)(row + r) * 1024 + col] = acc[mi][ni][r] + bias;
    }
  }
}

// ---------------- phase 2+3 fused persistent kernel ----------------
// Grid 256 x 256thr, __launch_bounds__(256,2): all blocks co-resident by
// construction. Blocks 0..63: r5-proven rnn role. Blocks 64..255: 192 logits
// workers, 128x128 tiles (r10 geometry). Interference control vs r11:
//  - gate = ONE lane polling ONE flag line (bid-spread), s_sleep(127); uses
//    the protocol invariant flag[j]=v => all slots <= v-1 globally published.
//    Only tIdx=255 tiles need the all-64-flags poll at 1024 (final post).
//  - 128x128 tiles halve L3 re-read traffic vs 128x64.
//  - 192 workers (not 960): release pace bounds throughput, not workers.
__global__ __launch_bounds__(256, 2) void k_fused(const u16* __restrict__ WhhT,
                                                  const float* __restrict__ xpart,
                                                  u16* __restrict__ ring,
                                                  float* __restrict__ hfinal,
                                                  unsigned* flags,
                                                  const u16* __restrict__ WoT,
                                                  const float* __restrict__ bo,
                                                  float* __restrict__ C) {
  __shared__ __align__(16) u16 smem[8192];        // union: rnn psh 8KB | As 8KB + Bs 8KB
  __shared__ int sq;
  const int tid = threadIdx.x, lane = tid & 63, w = tid >> 6;

  if (blockIdx.x < 64) {
    // ================= rnn role (r5 structure, verbatim) =================
    float* psh = (float*)smem;
    int bid = blockIdx.x;
    int jbase = bid * 16;
    const int rl = lane & 15;
    const int kbase = w * 256 + ((lane >> 4) << 3);
    bf16x8 Wreg[8];
    #pragma unroll
    for (int ki = 0; ki < 8; ++ki)
      Wreg[ki] = *(const bf16x8*)&WhhT[(size_t)(jbase + rl) * 1024 + kbase + ki * 32];
    const bool red = (tid < 128);
    int b = 0, jq = 0, mi = 0, lsrc = 0, rg = 0;
    float4 xpre = make_float4(0.f, 0.f, 0.f, 0.f);
    if (red) {
      b = tid >> 2; jq = (tid & 3) << 2;
      mi = b >> 4;
      int bb = b & 15;
      lsrc = (bb >> 2) << 4;
      rg = bb & 3;
      xpre = *(const float4*)&xpart[(size_t)(b * 1024 + 0) * 1024 + jbase + jq];
    }
    for (int t = 0; t < 1024; ++t) {
      const u16* hprev = ring + (size_t)t * 32768;
      bf16x8 ha[16];
      #pragma unroll
      for (int ki = 0; ki < 8; ++ki) {
        int k = kbase + ki * 32;
        ha[ki*2 + 0] = *(const bf16x8*)&hprev[(size_t)rl * 1024 + k];
        ha[ki*2 + 1] = *(const bf16x8*)&hprev[(size_t)(16 + rl) * 1024 + k];
      }
      f32x4 acc0 = {0.f, 0.f, 0.f, 0.f}, acc1 = {0.f, 0.f, 0.f, 0.f};
      #pragma unroll
      for (int ki = 0; ki < 8; ++ki) {
        acc0 = mfma16(ha[ki*2 + 0], Wreg[ki], acc0);
        acc1 = mfma16(ha[ki*2 + 1], Wreg[ki], acc1);
      }
      *(f32x4*)&psh[((w * 2 + 0) * 64 + lane) * 4] = acc0;
      *(f32x4*)&psh[((w * 2 + 1) * 64 + lane) * 4] = acc1;
      __syncthreads();
      if (red) {
        float s0 = 0.f, s1 = 0.f, s2 = 0.f, s3 = 0.f;
        #pragma unroll
        for (int ww = 0; ww < 4; ++ww) {
          const float* pp = &psh[((ww * 2 + mi) * 64) * 4];
          s0 += pp[(lsrc + jq + 0) * 4 + rg];
          s1 += pp[(lsrc + jq + 1) * 4 + rg];
          s2 += pp[(lsrc + jq + 2) * 4 + rg];
          s3 += pp[(lsrc + jq + 3) * 4 + rg];
        }
        float v0 = tanhf(s0 + xpre.x);
        float v1 = tanhf(s1 + xpre.y);
        float v2 = tanhf(s2 + xpre.z);
        float v3 = tanhf(s3 + xpre.w);
        u32 lo = (u32)f2bf(v0) | ((u32)f2bf(v1) << 16);
        u32 hi = (u32)f2bf(v2) | ((u32)f2bf(v3) << 16);
        u64 hv = (u64)lo | ((u64)hi << 32);
        __hip_atomic_store((u64*)(ring + (size_t)(t + 1) * 32768 + b * 1024 + jbase + jq),
                           hv, __ATOMIC_RELAXED, __HIP_MEMORY_SCOPE_AGENT);
        if (t == 1023)
          *(float4*)&hfinal[b * 1024 + jbase + jq] = make_float4(v0, v1, v2, v3);
      }
      if (t < 1023) {
        asm volatile("s_waitcnt vmcnt(0)" ::: "memory");
        __syncthreads();
        if (tid == 0)
          __hip_atomic_store(&flags[bid * 32], (unsigned)(t + 1),
                             __ATOMIC_RELAXED, __HIP_MEMORY_SCOPE_AGENT);
        if (red)
          xpre = *(const float4*)&xpart[((size_t)(b * 1024 + (t + 1))) * 1024 + jbase + jq];
        if (w == 0) {
          while (__hip_atomic_load(&flags[lane * 32], __ATOMIC_RELAXED,
                                   __HIP_MEMORY_SCOPE_AGENT) < (unsigned)(t + 1)) { }
        }
        __syncthreads();
      } else {
        // final publish: slot 1024 drained -> flag 1024 (workers' last gate)
        asm volatile("s_waitcnt vmcnt(0)" ::: "memory");
        __syncthreads();
        if (tid == 0)
          __hip_atomic_store(&flags[bid * 32], 1024u,
                             __ATOMIC_RELAXED, __HIP_MEMORY_SCOPE_AGENT);
      }
    }
    return;
  }

  // ================= logits worker role (128x128 tiles) =================
  u16* As = smem;                 // 128x32
  u16* Bs = smem + 4096;          // 128x32
  unsigned* qctr = flags + 2047;
  const u16* A = ring + 32768;    // A row m -> (t=m>>5, b=m&31)
  const int wm = (w >> 1) * 64, wn = (w & 1) * 64;
  const int r0 = tid >> 2, sub = tid & 3;
  const int rl = lane & 15, kb = (lane >> 4) * 8;
  const int rq = (lane >> 4) << 2;
  const unsigned* myflag = flags + (blockIdx.x & 63) * 32;   // bid-spread line
  for (;;) {
    if (tid == 0)
      sq = (int)__hip_atomic_fetch_add(qctr, 1u, __ATOMIC_RELAXED,
                                       __HIP_MEMORY_SCOPE_AGENT);
    __syncthreads();
    const int q = sq;
    if (q >= 16384) return;
    const int tIdx = q >> 6, vIdx = q & 63;
    const int tm = tIdx * 128, tn = vIdx * 128;
    // ---- gate (low-pressure) ----
    if (tIdx < 255) {
      // invariant: flag[j] = v  =>  all ring slots <= v-1 published globally
      if (tid == 0) {
        unsigned tgt = (unsigned)(tIdx * 4 + 5);
        while (__hip_atomic_load(myflag, __ATOMIC_RELAXED,
                                 __HIP_MEMORY_SCOPE_AGENT) < tgt)
          __builtin_amdgcn_s_sleep(127);
      }
    } else {
      // last t-row needs slot 1024 from ALL blocks: all 64 flags == 1024
      if (tid < 64) {
        const unsigned* fp = flags + tid * 32;
        for (;;) {
          unsigned v = __hip_atomic_load(fp, __ATOMIC_RELAXED, __HIP_MEMORY_SCOPE_AGENT);
          if (!__any((int)(v < 1024u))) break;
          __builtin_amdgcn_s_sleep(127);
        }
      }
    }
    __syncthreads();
    // ---- compute 128x128 tile ----
    const u16* ga0 = A + (size_t)(tm + r0) * 1024 + sub * 8;
    const u16* ga1 = A + (size_t)(tm + 64 + r0) * 1024 + sub * 8;
    const u16* gb0 = WoT + (size_t)(tn + r0) * 1024 + sub * 8;
    const u16* gb1 = WoT + (size_t)(tn + 64 + r0) * 1024 + sub * 8;
    f32x4 acc[4][4] = {};
    for (int kt = 0; kt < 32; ++kt) {
      int k0 = kt * 32;
      __syncthreads();
      GLOAD16(ga0 + k0, As + w * 512);
      GLOAD16(ga1 + k0, As + 2048 + w * 512);
      GLOAD16(gb0 + k0, Bs + w * 512);
      GLOAD16(gb1 + k0, Bs + 2048 + w * 512);
      __syncthreads();
      bf16x8 af[4], bf[4];
      #pragma unroll
      for (int mi = 0; mi < 4; mi++) af[mi] = *(const bf16x8*)&As[(wm + mi*16 + rl) * 32 + kb];
      #pragma unroll
      for (int ni = 0; ni < 4; ni++) bf[ni] = *(const bf16x8*)&Bs[(wn + ni*16 + rl) * 32 + kb];
      #pragma unroll
      for (int mi = 0; mi < 4; mi++)
        #pragma unroll
        for (int ni = 0; ni < 4; ni++)
          acc[mi][ni] = mfma16(af[mi], bf[ni], acc[mi][ni]);
    }
    #pragma unroll
    for (int ni = 0; ni < 4; ni++) {
      int col = tn + wn + ni*16 + rl;
      float bias = bo[col];
      #pragma unroll
      for (int mi = 0; mi < 4; mi++) {
        int row = tm + wm + mi*16 + rq;
        #pragma unroll
        for (int r = 0; r < 4; r++) {
          int m = row + r;
          size_t orow = (size_t)(((m & 31) << 10) | (m >> 5));
          C[orow * 8192 + col] = acc[mi][ni][r] + bias;
        }
      }
    }
  }
}

// ---------------- launch ----------------
extern "C" void kernel_launch(void* const* d_in, const int* in_sizes, int n_in,
                              void* d_out, int out_size, void* d_ws, size_t ws_size,
                              hipStream_t stream) {
  const int*   x   = (const int*)  d_in[0];
  const float* hid = (const float*)d_in[1];
  const float* emb = (const float*)d_in[2];
  const float* Wh  = (const float*)d_in[3];
  const float* bh  = (const float*)d_in[4];
  const float* Wo  = (const float*)d_in[5];
  const float* bo  = (const float*)d_in[6];
  float* logits = (float*)d_out;                       // [32768][8192]
  float* hfinal = logits + (size_t)32768 * 8192;       // [32][1024]

  char* ws = (char*)d_ws;
  size_t off = 0;
  auto alloc = [&](size_t bytes) {
    char* p = ws + off;
    off += (bytes + 255) & ~(size_t)255;
    return p;
  };
  u16*   embB  = (u16*)  alloc((size_t)8192 * 512 * 2);    //  8 MB
  u16*   WhxT  = (u16*)  alloc((size_t)1024 * 512 * 2);    //  1 MB
  u16*   WhhT  = (u16*)  alloc((size_t)1024 * 1024 * 2);   //  2 MB
  u16*   WoT   = (u16*)  alloc((size_t)8192 * 1024 * 2);   // 16 MB
  float* xpart = (float*)alloc((size_t)32768 * 1024 * 4);  // 128 MB, row=b*1024+t
  u16*   ring  = (u16*)  alloc((size_t)1025 * 32768 * 2);  // 67.1 MB (slot t = h_t)
  unsigned* flags = (unsigned*)alloc(8192);                // 64 flags + qctr
  (void)ws_size; (void)in_sizes; (void)n_in; (void)out_size;

  k_cvt_emb<<<4096, 256, 0, stream>>>(emb, embB);
  k_tr_wh  <<<1536, 256, 0, stream>>>(Wh, WhxT, WhhT);
  k_tr_wo  <<<8192, 256, 0, stream>>>(Wo, WoT);
  k_init   <<<128,  256, 0, stream>>>(hid, ring, flags);
  k_xpart  <<<2048, 256, 0, stream>>>(x, embB, WhxT, bh, xpart);
  k_fused  <<<256,  256, 0, stream>>>(WhhT, xpart, ring, hfinal, flags,
                                      WoT, bo, logits);
}